// Round 5
// baseline (604.780 us; speedup 1.0000x reference)
//
#include <hip/hip_runtime.h>
#include <hip/hip_bf16.h>

#define B_  8
#define T_  4096
#define D_  1024
#define M_  (B_*T_)   // 32768
#define N_  (2*D_)    // 2048
#define K_  D_        // 1024
#define NC_ 32        // chunks over T
#define C_  (T_/NC_)  // 128 steps per chunk

typedef short bf16x8 __attribute__((ext_vector_type(8)));
typedef float f32x4  __attribute__((ext_vector_type(4)));

__device__ __forceinline__ unsigned short f2bf(float f) {
  union { float f; unsigned int u; } v; v.f = f;
  unsigned int r = (v.u + 0x7fffu + ((v.u >> 16) & 1u)) >> 16;
  return (unsigned short)r;
}

__device__ __forceinline__ float bf2f(unsigned short u) {
  union { unsigned int u; float f; } v; v.u = ((unsigned int)u) << 16; return v.f;
}

// packed bf16 pair -> floats (lo = bits 0-15, hi = bits 16-31; hi needs no shift)
__device__ __forceinline__ float bflo(unsigned int u) {
  union { unsigned int u; float f; } v; v.u = u << 16; return v.f;
}
__device__ __forceinline__ float bfhi(unsigned int u) {
  union { unsigned int u; float f; } v; v.u = u & 0xffff0000u; return v.f;
}

__device__ __forceinline__ float sigm(float x) {
  return 1.0f / (1.0f + __expf(-x));
}

// async global->LDS, 16B per lane; lds base must be wave-uniform
__device__ __forceinline__ void async16(const void* g, void* l) {
  __builtin_amdgcn_global_load_lds((const __attribute__((address_space(1))) void*)g,
                                   (__attribute__((address_space(3))) void*)l,
                                   16, 0, 0);
}

// ---------------- cast kernel (W only; x-cast is fused into the GEMM) --------
// W [K, N] fp32 -> Wt [N, K] bf16 (tiled transpose)
__global__ void cast_wt_kernel(const float* __restrict__ W, unsigned short* __restrict__ Wt) {
  __shared__ float tile[32][33];
  const int n0 = blockIdx.x * 32, k0 = blockIdx.y * 32;
  const int tx = threadIdx.x, ty = threadIdx.y; // (32, 8)
  for (int i = 0; i < 32; i += 8)
    tile[ty + i][tx] = W[(size_t)(k0 + ty + i) * N_ + n0 + tx];
  __syncthreads();
  for (int i = 0; i < 32; i += 8)
    Wt[(size_t)(n0 + ty + i) * K_ + k0 + tx] = f2bf(tile[tx][ty + i]);
}

// ---------------- GEMM: 256x256 tile, 8-phase lockstep, counted vmcnt ----------
// P = x @ Wt^T + bias (A read as f32, converted to bf16 during reg-staging —
// bit-identical LDS image to the old cast_x + async16 path), fused gate
// epilogue, bf16 out via LDS-transpose stores.
#define BM 256
#define BN 256
#define BK 64
#define LDSA(b) ((b)*32768)      // elem offset of A region of buffer b
#define LDSB(b) ((b)*32768 + 16384)

#define BARX()  __builtin_amdgcn_s_barrier()
#define LGKM0() asm volatile("s_waitcnt lgkmcnt(0)" ::: "memory")
#define LGKM8() asm volatile("s_waitcnt lgkmcnt(8)" ::: "memory")
#define SB0()   __builtin_amdgcn_sched_barrier(0)
#define VM8()   asm volatile("s_waitcnt vmcnt(8)" ::: "memory")
#define VM0()   asm volatile("s_waitcnt vmcnt(0)" ::: "memory")

// B staging: 4 async16 rounds, wave-uniform LDS base, pre-swizzled global src.
#define STAGE_Bt(BUF, KOFF) do {                                                \
    _Pragma("unroll")                                                           \
    for (int r = 0; r < 4; ++r)                                                 \
      async16(aB + (KOFF) + r*64*K_, lds + LDSB(BUF) + w*512 + r*4096);         \
  } while (0)

// A staging, reg-staged f32 -> bf16 (replaces cast_x + async16):
//  LOAD: 8 float4 loads (rows r*64 + w*8 + lr, cols KOFF + (lg^lr)*8 .. +8).
//  WRITE: cvt + ds_write_b128 to the SAME LDS addresses async16 produced
//  (elem off = r*4096 + w*512 + lane*8). Issued LOAD at P1-top (older than the
//  tile's B-asyncs) so the compiler's implicit wait before WRITE is vmcnt(4) —
//  B stays in flight; that wait also drains the PREVIOUS tile's B-asyncs,
//  subsuming the old VM8 buffer-swap invariant.
#define STAGE_A_LOAD(KOFF) do {                                                 \
    _Pragma("unroll")                                                           \
    for (int r = 0; r < 4; ++r) {                                               \
      av0[r] = *(const float4*)(aAx + (KOFF) + r*64*K_);                        \
      av1[r] = *(const float4*)(aAx + (KOFF) + r*64*K_ + 4);                    \
    } } while (0)
#define STAGE_A_WRITE(BUF) do {                                                 \
    _Pragma("unroll")                                                           \
    for (int r = 0; r < 4; ++r) {                                               \
      bf16x8 pk;                                                                \
      pk[0] = (short)f2bf(av0[r].x); pk[1] = (short)f2bf(av0[r].y);             \
      pk[2] = (short)f2bf(av0[r].z); pk[3] = (short)f2bf(av0[r].w);             \
      pk[4] = (short)f2bf(av1[r].x); pk[5] = (short)f2bf(av1[r].y);             \
      pk[6] = (short)f2bf(av1[r].z); pk[7] = (short)f2bf(av1[r].w);             \
      *(bf16x8*)(lds + LDSA(BUF) + r*4096 + w*512 + lane*8) = pk;               \
    } } while (0)

#define RD_A(MBASE, BUF) do {                                                   \
    _Pragma("unroll")                                                           \
    for (int m = 0; m < 4; ++m) {                                               \
      af[m][0] = *(const bf16x8*)(lds + LDSA(BUF) + (rowA + (MBASE + m)*16)*64 + cc0); \
      af[m][1] = *(const bf16x8*)(lds + LDSA(BUF) + (rowA + (MBASE + m)*16)*64 + cc1); \
    } } while (0)
#define RD_B(NBASE, BUF) do {                                                   \
    _Pragma("unroll")                                                           \
    for (int n = 0; n < 2; ++n) {                                               \
      bfr[NBASE + n][0] = *(const bf16x8*)(lds + LDSB(BUF) + (rowB + (NBASE + n)*16)*64 + cc0); \
      bfr[NBASE + n][1] = *(const bf16x8*)(lds + LDSB(BUF) + (rowB + (NBASE + n)*16)*64 + cc1); \
    } } while (0)

#define MFMA_Q(MB, NB) do {                                                     \
    __builtin_amdgcn_s_setprio(1);                                              \
    _Pragma("unroll")                                                           \
    for (int m = 0; m < 4; ++m)                                                 \
      _Pragma("unroll")                                                         \
      for (int n = 0; n < 2; ++n) {                                             \
        acc[MB+m][NB+n] = __builtin_amdgcn_mfma_f32_16x16x32_bf16(af[m][0], bfr[NB+n][0], acc[MB+m][NB+n], 0, 0, 0); \
        acc[MB+m][NB+n] = __builtin_amdgcn_mfma_f32_16x16x32_bf16(af[m][1], bfr[NB+n][1], acc[MB+m][NB+n], 0, 0, 0); \
      }                                                                         \
    __builtin_amdgcn_s_setprio(0);                                              \
  } while (0)

// One K-tile = 4 phases, staging the next-NEXT tile into THIS buffer
// (2-tile lookahead). A-loads issue at P1 (regs, no LDS hazard); B asyncs at
// P2 (B-region free after P1's trailing barrier); A cvt+ds_write at P3
// (A-region free after P2's trailing barrier; cross-wave WAR safe because
// every wave's P2 ds_reads complete before it passes the P2-trailing barrier).
// ds_writes drain via this wave's own LGKM0 at the next tile's P0, which
// happens well before any wave reads the staged region at tile t+2.
#define TILE(BUF, DO_STAGE, KOFF, VMW) do {                                     \
    /* P0 */                                                                    \
    RD_A(0, BUF); RD_B(0, BUF);                                                 \
    LGKM8();                                                                    \
    BARX(); LGKM0(); SB0();                                                     \
    MFMA_Q(0, 0);                                                               \
    BARX();                                                                     \
    /* P1 */                                                                    \
    if (DO_STAGE) STAGE_A_LOAD(KOFF);                                           \
    RD_B(2, BUF);                                                               \
    BARX(); LGKM0(); SB0();                                                     \
    MFMA_Q(0, 2);                                                               \
    BARX();                                                                     \
    /* P2 */                                                                    \
    if (DO_STAGE) STAGE_Bt(BUF, KOFF);                                          \
    RD_A(4, BUF);                                                               \
    BARX(); LGKM0(); SB0();                                                     \
    MFMA_Q(4, 0);                                                               \
    BARX();                                                                     \
    /* P3 */                                                                    \
    if (DO_STAGE) STAGE_A_WRITE(BUF);                                           \
    MFMA_Q(4, 2);                                                               \
    VMW;                                                                        \
    BARX();                                                                     \
  } while (0)

__global__ __launch_bounds__(512, 2) void gemm_kernel(
    const float* __restrict__ X,
    const unsigned short* __restrict__ Bt,
    const float* __restrict__ bias,
    unsigned short* __restrict__ Sout,
    unsigned short* __restrict__ Gout) {
  __shared__ unsigned short lds[65536];   // 128 KB: 2 bufs x (A 16K + B 16K elems)

  const int tid  = threadIdx.x;
  const int w    = tid >> 6;      // wave 0..7
  const int lane = tid & 63;
  const int wm   = w >> 2;        // 0..1  (128 rows each)
  const int wn   = w & 3;         // 0..3  (64 cols each)
  const int quad = lane >> 4, n15 = lane & 15;

  // XCD-aware swizzle: all 8 n-blocks of an m-tile stay on one XCD, consecutive.
  const int bid   = blockIdx.x;          // 0..1023
  const int xcd   = bid & 7;
  const int j     = bid >> 3;            // 0..127
  const int n_idx = j & 7;
  const int m_idx = (j >> 3) * 8 + xcd;  // 0..127
  const int m0 = m_idx * BM, n0 = n_idx * BN;

  // staging lane geometry: lane covers row (w*8 + lr), 16B group lg, source
  // column group pre-swizzled by lg ^ (row&7) so LDS stays linear.
  const int lr = lane >> 3, lg = lane & 7;
  const int sg8 = (lg ^ lr) * 8;
  const float*          aAx = X  + (size_t)(m0 + w*8 + lr) * K_ + sg8;  // f32 source
  const unsigned short* aB  = Bt + (size_t)(n0 + w*8 + lr) * K_ + sg8;

  // fragment-read offsets: row&7 == n15&7 for all fragment rows
  const int n7  = n15 & 7;
  const int cc0 = (quad ^ n7) * 8;   // k-slice 0
  const int cc1 = cc0 ^ 32;          // k-slice 1 (group ^ 4)
  const int rowA = wm * 128 + n15;
  const int rowB = wn * 64  + n15;

  f32x4 acc[8][4];
  #pragma unroll
  for (int i = 0; i < 8; ++i)
    #pragma unroll
    for (int jj = 0; jj < 4; ++jj) acc[i][jj] = (f32x4){0.f, 0.f, 0.f, 0.f};

  bf16x8 af[4][2], bfr[4][2];
  float4 av0[4], av1[4];

  // prologue: tile0 A-loads (oldest), B asyncs for tiles 0+1, A0 write
  // (implicit vmcnt(8) leaves B in flight), tile1 A load+write (drains all),
  // lgkm drain for the ds_writes, barrier.
  STAGE_A_LOAD(0);
  STAGE_Bt(0, 0);
  STAGE_Bt(1, 64);
  STAGE_A_WRITE(0);
  STAGE_A_LOAD(64);
  STAGE_A_WRITE(1);
  LGKM0();
  VM0();
  BARX();

  int koff = 128;   // k elem offset of next staged tile (tile 2)
  #pragma unroll 1
  for (int it = 0; it < 7; ++it) {
    TILE(0, 1, koff,      VM8());
    TILE(1, 1, koff + 64, VM8());
    koff += 128;
  }
  TILE(0, 0, 0, VM0());     // tile 14; drain so tile 15 is landed
  TILE(1, 0, 0, ((void)0)); // tile 15

  // ---- epilogue: bias + gate, LDS transpose (XOR-swizzled), wide stores ----
  const bool is_k = (n0 >= D_);
  unsigned short* __restrict__ dst = is_k ? Sout : Gout;
  const int d0 = is_k ? (n0 - D_) : n0;
  float bv[4];
  #pragma unroll
  for (int jj = 0; jj < 4; ++jj) bv[jj] = bias[n0 + wn*64 + jj*16 + n15];

  #pragma unroll
  for (int i = 0; i < 8; ++i) {
    #pragma unroll
    for (int jj = 0; jj < 4; ++jj) {
      const int col = wn*64 + jj*16 + n15;          // block-local col
      #pragma unroll
      for (int r = 0; r < 4; ++r) {
        const int row = wm*128 + i*16 + quad*4 + r; // block-local row
        const float val = acc[i][jj][r] + bv[jj];
        const float o = is_k ? sigm(val)
                             : ((val >= 0.0f) ? (val + 0.5f) : sigm(val));
        const int slot = (col >> 3) ^ (row & 7);    // 8-elem-group XOR swizzle
        lds[row*256 + slot*8 + (col & 7)] = f2bf(o);
      }
    }
  }
  __syncthreads();
  const int trow = tid >> 5;   // 0..15
  const int cg   = tid & 31;   // 16B group within row
  #pragma unroll
  for (int rr = 0; rr < 16; ++rr) {
    const int row = rr*16 + trow;
    const uint4 v = *(const uint4*)(lds + row*256 + ((cg ^ (row & 7)) * 8));
    *(uint4*)(dst + (size_t)(m0 + row) * D_ + d0 + cg*8) = v;
  }
}

// ---------------- pass 1: per-chunk aggregates (vectorized: 2 cols/thread) ----
__global__ void chunk_agg_kernel(const unsigned short* __restrict__ S,
                                 const unsigned short* __restrict__ G,
                                 float* __restrict__ AggA, float* __restrict__ AggV) {
  const int p = blockIdx.x * 256 + threadIdx.x;   // pair index 0..511
  const int d = p * 2;
  const int c = blockIdx.y;
  const int b = blockIdx.z;
  size_t base2 = ((((size_t)b * T_ + (size_t)c * C_) * D_) + d) >> 1;  // uint index
  const unsigned int* __restrict__ S2 = (const unsigned int*)S;
  const unsigned int* __restrict__ G2 = (const unsigned int*)G;
  float Aa0 = 1.0f, V0 = 0.0f, Aa1 = 1.0f, V1 = 0.0f;
  for (int t = 0; t < C_; ++t) {
    const unsigned int sv = S2[base2];
    const unsigned int gv = G2[base2];
    const float s0 = bflo(sv), s1 = bfhi(sv);
    const float g0 = bflo(gv), g1 = bfhi(gv);
    const float a0 = 1.0f - s0, a1 = 1.0f - s1;
    V0 = fmaf(a0, V0, s0 * g0);
    V1 = fmaf(a1, V1, s1 * g1);
    Aa0 *= a0; Aa1 *= a1;
    base2 += D_ / 2;
  }
  const int idx = (b * NC_ + c) * D_ + d;
  *(float2*)(AggA + idx) = make_float2(Aa0, Aa1);
  *(float2*)(AggV + idx) = make_float2(V0, V1);
}

// ---------------- pass 2: exclusive scan over chunk aggregates (float2) -------
__global__ void chunk_scan_kernel(const float* __restrict__ AggA, const float* __restrict__ AggV,
                                  float* __restrict__ H0) {
  const int p = blockIdx.x * 256 + threadIdx.x;   // 0..511
  const int d = p * 2;
  const int b = blockIdx.y;
  float h0 = 0.0f, h1 = 0.0f;
  for (int c = 0; c < NC_; ++c) {
    const int idx = (b * NC_ + c) * D_ + d;
    const float2 a = *(const float2*)(AggA + idx);
    const float2 v = *(const float2*)(AggV + idx);
    *(float2*)(H0 + idx) = make_float2(h0, h1);
    h0 = fmaf(a.x, h0, v.x);
    h1 = fmaf(a.y, h1, v.y);
  }
}

// ---------------- pass 3: replay scan + residual + LayerNorm, phase-swapped ----
// Batches of 16 t: phase 1 (thread = d) scans 16 steps into LDS y-buffer;
// phase 2 (wave = t) does the LN with wave shuffles; float2 LDS reads (2-way
// bank aliasing = free) and float2 coalesced output stores.
__global__ __launch_bounds__(1024, 1) void scan_ln_kernel(
    const unsigned short* __restrict__ S, const unsigned short* __restrict__ G,
    const float* __restrict__ x, const float* __restrict__ H0,
    const float* __restrict__ gamma, const float* __restrict__ beta,
    float* __restrict__ out) {
  __shared__ float yb[16 * 1024];
  const int d = threadIdx.x;         // 0..1023
  const int c = blockIdx.x;
  const int b = blockIdx.y;
  const int wid = d >> 6, lane = d & 63;

  float h = H0[(b * NC_ + c) * D_ + d];
  // LN-phase mapping: this thread covers d2 = lane*2 + 128*j (float2 lanes)
  float2 gam2[8], bet2[8];
  for (int j = 0; j < 8; ++j) {
    gam2[j] = *(const float2*)(gamma + lane * 2 + 128 * j);
    bet2[j] = *(const float2*)(beta  + lane * 2 + 128 * j);
  }

  size_t base = ((size_t)b * T_ + (size_t)c * C_) * D_ + d;
  for (int batch = 0; batch < 8; ++batch) {
    // phase 1: sequential scan of 16 timesteps, y -> LDS
    for (int tt = 0; tt < 16; ++tt) {
      const size_t idx = base + (size_t)tt * D_;
      const float s = bf2f(S[idx]);
      const float g = bf2f(G[idx]);
      h = fmaf(s, g - h, h);           // (1-s)*h + s*g
      yb[tt * 1024 + d] = x[idx] + h;
    }
    __syncthreads();
    // phase 2: wave `wid` handles local timestep t = wid
    {
      float sy = 0.0f, sq = 0.0f;
      float2 yv[8];
      for (int j = 0; j < 8; ++j) {
        const float2 v = *(const float2*)(&yb[wid * 1024 + lane * 2 + 128 * j]);
        yv[j] = v;
        sy += v.x + v.y;
        sq += v.x * v.x + v.y * v.y;
      }
      for (int o = 32; o > 0; o >>= 1) {
        sy += __shfl_down(sy, o);
        sq += __shfl_down(sq, o);
      }
      sy = __shfl(sy, 0); sq = __shfl(sq, 0);
      const float mu   = sy * (1.0f / D_);
      const float rstd = rsqrtf(sq * (1.0f / D_) - mu * mu + 1e-6f);
      const size_t obase = ((size_t)b * T_ + (size_t)c * C_ + (size_t)batch * 16 + wid) * D_;
      for (int j = 0; j < 8; ++j) {
        float2 o2;
        o2.x = (yv[j].x - mu) * rstd * gam2[j].x + bet2[j].x;
        o2.y = (yv[j].y - mu) * rstd * gam2[j].y + bet2[j].y;
        *(float2*)(out + obase + lane * 2 + 128 * j) = o2;
      }
    }
    __syncthreads();
    base += (size_t)16 * D_;
  }
}

// ---------------- launcher ----------------
extern "C" void kernel_launch(void* const* d_in, const int* in_sizes, int n_in,
                              void* d_out, int out_size, void* d_ws, size_t ws_size,
                              hipStream_t stream) {
  const float* x     = (const float*)d_in[0];
  const float* W     = (const float*)d_in[1];
  const float* bias  = (const float*)d_in[2];
  const float* gamma = (const float*)d_in[3];
  const float* beta  = (const float*)d_in[4];
  float* out = (float*)d_out;

  char* ws = (char*)d_ws;
  unsigned short* Wt = (unsigned short*)ws;  ws += (size_t)N_ * K_ * 2;        // 4 MB
  unsigned short* S  = (unsigned short*)ws;  ws += (size_t)M_ * D_ * 2;        // 64 MB
  unsigned short* G  = (unsigned short*)ws;  ws += (size_t)M_ * D_ * 2;        // 64 MB
  float* AggA = (float*)ws;                  ws += (size_t)B_ * NC_ * D_ * 4;  // 1 MB
  float* AggV = (float*)ws;                  ws += (size_t)B_ * NC_ * D_ * 4;  // 1 MB
  float* H0   = (float*)ws;                  ws += (size_t)B_ * NC_ * D_ * 4;  // 1 MB

  cast_wt_kernel<<<dim3(N_ / 32, K_ / 32), dim3(32, 8), 0, stream>>>(W, Wt);
  gemm_kernel<<<1024, 512, 0, stream>>>(x, Wt, bias, S, G);
  chunk_agg_kernel<<<dim3(D_ / 512, NC_, B_), 256, 0, stream>>>(S, G, AggA, AggV);
  chunk_scan_kernel<<<dim3(D_ / 512, B_), 256, 0, stream>>>(AggA, AggV, H0);
  scan_ln_kernel<<<dim3(NC_, B_), 1024, 0, stream>>>(S, G, x, H0, gamma, beta, out);
}

// Round 6
// 473.833 us; speedup vs baseline: 1.2764x; 1.2764x over previous
//
#include <hip/hip_runtime.h>
#include <hip/hip_bf16.h>

#define B_  8
#define T_  4096
#define D_  1024
#define M_  (B_*T_)   // 32768
#define N_  (2*D_)    // 2048
#define K_  D_        // 1024
#define NC_ 32        // chunks over T
#define C_  (T_/NC_)  // 128 steps per chunk

typedef short bf16x8 __attribute__((ext_vector_type(8)));
typedef float f32x4  __attribute__((ext_vector_type(4)));

__device__ __forceinline__ unsigned short f2bf(float f) {
  union { float f; unsigned int u; } v; v.f = f;
  unsigned int r = (v.u + 0x7fffu + ((v.u >> 16) & 1u)) >> 16;
  return (unsigned short)r;
}

__device__ __forceinline__ float bf2f(unsigned short u) {
  union { unsigned int u; float f; } v; v.u = ((unsigned int)u) << 16; return v.f;
}

__device__ __forceinline__ float sigm(float x) {
  return 1.0f / (1.0f + __expf(-x));
}

// async global->LDS, 16B per lane; lds base must be wave-uniform
__device__ __forceinline__ void async16(const void* g, void* l) {
  __builtin_amdgcn_global_load_lds((const __attribute__((address_space(1))) void*)g,
                                   (__attribute__((address_space(3))) void*)l,
                                   16, 0, 0);
}

// ---------------- cast kernels ----------------
__global__ void cast_x_kernel(const float* __restrict__ x, unsigned short* __restrict__ xb) {
  const long n4 = (long)M_ * K_ / 4;
  long i = (long)blockIdx.x * blockDim.x + threadIdx.x;
  const long stride = (long)gridDim.x * blockDim.x;
  for (; i < n4; i += stride) {
    float4 v = ((const float4*)x)[i];
    ushort4 o;
    o.x = f2bf(v.x); o.y = f2bf(v.y); o.z = f2bf(v.z); o.w = f2bf(v.w);
    ((ushort4*)xb)[i] = o;
  }
}

// W [K, N] fp32 -> Wt [N, K] bf16 (tiled transpose)
__global__ void cast_wt_kernel(const float* __restrict__ W, unsigned short* __restrict__ Wt) {
  __shared__ float tile[32][33];
  const int n0 = blockIdx.x * 32, k0 = blockIdx.y * 32;
  const int tx = threadIdx.x, ty = threadIdx.y; // (32, 8)
  for (int i = 0; i < 32; i += 8)
    tile[ty + i][tx] = W[(size_t)(k0 + ty + i) * N_ + n0 + tx];
  __syncthreads();
  for (int i = 0; i < 32; i += 8)
    Wt[(size_t)(n0 + ty + i) * K_ + k0 + tx] = f2bf(tile[tx][ty + i]);
}

// ---------------- GEMM: P = Xb @ Wt^T + bias, fused gate epilogue, bf16 out ----------------
#define BM 128
#define BN 128
#define BK 64

__global__ __launch_bounds__(256, 3) void gemm_kernel(
    const unsigned short* __restrict__ A,
    const unsigned short* __restrict__ Bt,
    const float* __restrict__ bias,
    unsigned short* __restrict__ Sout,
    unsigned short* __restrict__ Gout) {
  __shared__ unsigned short lds[2 * BM * BK];
  unsigned short* As = lds;
  unsigned short* Bs = lds + BM * BK;

  const int tid  = threadIdx.x;
  const int wave = tid >> 6;
  const int lane = tid & 63;

  // XCD-aware swizzle: dispatch id i -> xcd = i&7 (round-robin). Keep all 16
  // n-blocks of one m-tile on the same XCD, consecutive in its queue, so the
  // 256 KB A-tile is HBM-fetched once and L2-resident for its reuse group.
  const int bid   = blockIdx.x;          // 1-D grid of 4096
  const int xcd   = bid & 7;
  const int j     = bid >> 3;            // 0..511
  const int n_idx = j & 15;
  const int m_idx = (j >> 4) * 8 + xcd;  // 0..255
  const int m0 = m_idx * BM;
  const int n0 = n_idx * BN;

  const int wm = wave >> 1;        // 0..1
  const int wn = wave & 1;         // 0..1
  const int n15  = lane & 15;
  const int quad = lane >> 4;

  f32x4 acc[4][4] = {};

  for (int k0 = 0; k0 < K_; k0 += BK) {
    // stage A tile [BM][BK] and B tile [BN][BK]; 16 segments of 512 elems each.
    // XOR swizzle: LDS (row, slot) holds global (row, slot ^ (row&7)) in 8-elem
    // (16B) groups -> fragment reads spread across all 32 banks.
    for (int i = 0; i < 4; ++i) {
      const int seg = wave * 4 + i;            // 0..15
      const int row = seg * 8 + (lane >> 3);   // 0..127
      const int gg  = ((lane & 7) ^ (row & 7)) * 8;
      async16(A  + (size_t)(m0 + row) * K_ + k0 + gg, As + seg * 512);
      async16(Bt + (size_t)(n0 + row) * K_ + k0 + gg, Bs + seg * 512);
    }
    __syncthreads();

    for (int kk = 0; kk < 2; ++kk) {
      const int gg = kk * 4 + quad;            // 16B group index of k-slice
      bf16x8 af[4], bfr[4];
      for (int i = 0; i < 4; ++i) {
        const int row = wm * 64 + i * 16 + n15;
        af[i] = *(const bf16x8*)(As + (size_t)row * BK + ((gg ^ (row & 7)) * 8));
      }
      for (int jj = 0; jj < 4; ++jj) {
        const int row = wn * 64 + jj * 16 + n15;
        bfr[jj] = *(const bf16x8*)(Bs + (size_t)row * BK + ((gg ^ (row & 7)) * 8));
      }
      for (int i = 0; i < 4; ++i)
        for (int jj = 0; jj < 4; ++jj)
          acc[i][jj] = __builtin_amdgcn_mfma_f32_16x16x32_bf16(af[i], bfr[jj], acc[i][jj], 0, 0, 0);
    }
    __syncthreads();
  }

  // epilogue; n-range of a block is entirely in one half (BN divides D_)
  const bool is_k = (n0 >= D_);
  unsigned short* __restrict__ dst = is_k ? Sout : Gout;
  for (int jj = 0; jj < 4; ++jj) {
    const int n = n0 + wn * 64 + jj * 16 + n15;
    const float bv = bias[n];
    const int d = is_k ? (n - D_) : n;
    for (int i = 0; i < 4; ++i) {
      const int mbase = m0 + wm * 64 + i * 16 + quad * 4;
      for (int r = 0; r < 4; ++r) {
        const float val = acc[i][jj][r] + bv;
        float o;
        if (is_k) o = sigm(val);                                // z = sigmoid(k)
        else      o = (val >= 0.0f) ? (val + 0.5f) : sigm(val); // g(h_tilde)
        dst[(size_t)(mbase + r) * D_ + d] = f2bf(o);
      }
    }
  }
}

// ---------------- pass 1: per-chunk aggregates ----------------
__global__ void chunk_agg_kernel(const unsigned short* __restrict__ S,
                                 const unsigned short* __restrict__ G,
                                 float* __restrict__ AggA, float* __restrict__ AggV) {
  const int d = blockIdx.x * 256 + threadIdx.x;
  const int c = blockIdx.y;
  const int b = blockIdx.z;
  size_t base = ((size_t)b * T_ + (size_t)c * C_) * D_ + d;
  float Aa = 1.0f, V = 0.0f;
  for (int t = 0; t < C_; ++t) {
    const float s = bf2f(S[base]);
    const float g = bf2f(G[base]);
    const float a = 1.0f - s;
    V = fmaf(a, V, s * g);
    Aa *= a;
    base += D_;
  }
  const int idx = (b * NC_ + c) * D_ + d;
  AggA[idx] = Aa;
  AggV[idx] = V;
}

// ---------------- pass 2: exclusive scan over chunk aggregates ----------------
__global__ void chunk_scan_kernel(const float* __restrict__ AggA, const float* __restrict__ AggV,
                                  float* __restrict__ H0) {
  const int d = blockIdx.x * 256 + threadIdx.x;
  const int b = blockIdx.y;
  float h = 0.0f;
  for (int c = 0; c < NC_; ++c) {
    const int idx = (b * NC_ + c) * D_ + d;
    H0[idx] = h;
    h = fmaf(AggA[idx], h, AggV[idx]);
  }
}

// ---------------- pass 3: replay scan + residual + LayerNorm, phase-swapped ----------------
// Batches of 16 t: phase 1 (thread = d) scans 16 steps into LDS y-buffer;
// phase 2 (wave = t) does the LN with pure wave shuffles. 2 barriers / 16 t.
__global__ __launch_bounds__(1024, 1) void scan_ln_kernel(
    const unsigned short* __restrict__ S, const unsigned short* __restrict__ G,
    const float* __restrict__ x, const float* __restrict__ H0,
    const float* __restrict__ gamma, const float* __restrict__ beta,
    float* __restrict__ out) {
  __shared__ float yb[16 * 1024];
  const int d = threadIdx.x;         // 0..1023
  const int c = blockIdx.x;
  const int b = blockIdx.y;
  const int wid = d >> 6, lane = d & 63;

  float h = H0[(b * NC_ + c) * D_ + d];
  // LN-phase mapping: this thread covers d2 = lane + 64*j (conflict-free LDS, coalesced stores)
  float gam[16], bet[16];
  for (int j = 0; j < 16; ++j) { gam[j] = gamma[lane + 64 * j]; bet[j] = beta[lane + 64 * j]; }

  size_t base = ((size_t)b * T_ + (size_t)c * C_) * D_ + d;
  for (int batch = 0; batch < 8; ++batch) {
    // phase 1: sequential scan of 16 timesteps, y -> LDS
    for (int tt = 0; tt < 16; ++tt) {
      const size_t idx = base + (size_t)tt * D_;
      const float s = bf2f(S[idx]);
      const float g = bf2f(G[idx]);
      h = fmaf(s, g - h, h);           // (1-s)*h + s*g
      yb[tt * 1024 + d] = x[idx] + h;
    }
    __syncthreads();
    // phase 2: wave `wid` handles local timestep t = wid
    {
      float sy = 0.0f, sq = 0.0f;
      float yv[16];
      for (int j = 0; j < 16; ++j) {
        const float v = yb[wid * 1024 + lane + 64 * j];
        yv[j] = v; sy += v; sq += v * v;
      }
      for (int o = 32; o > 0; o >>= 1) {
        sy += __shfl_down(sy, o);
        sq += __shfl_down(sq, o);
      }
      sy = __shfl(sy, 0); sq = __shfl(sq, 0);
      const float mu   = sy * (1.0f / D_);
      const float rstd = rsqrtf(sq * (1.0f / D_) - mu * mu + 1e-6f);
      const size_t obase = ((size_t)b * T_ + (size_t)c * C_ + (size_t)batch * 16 + wid) * D_;
      for (int j = 0; j < 16; ++j)
        out[obase + lane + 64 * j] = (yv[j] - mu) * rstd * gam[j] + bet[j];
    }
    __syncthreads();
    base += (size_t)16 * D_;
  }
}

// ---------------- launcher ----------------
extern "C" void kernel_launch(void* const* d_in, const int* in_sizes, int n_in,
                              void* d_out, int out_size, void* d_ws, size_t ws_size,
                              hipStream_t stream) {
  const float* x     = (const float*)d_in[0];
  const float* W     = (const float*)d_in[1];
  const float* bias  = (const float*)d_in[2];
  const float* gamma = (const float*)d_in[3];
  const float* beta  = (const float*)d_in[4];
  float* out = (float*)d_out;

  char* ws = (char*)d_ws;
  unsigned short* Wt = (unsigned short*)ws;  ws += (size_t)N_ * K_ * 2;        // 4 MB
  unsigned short* Xb = (unsigned short*)ws;  ws += (size_t)M_ * K_ * 2;        // 64 MB
  unsigned short* S  = (unsigned short*)ws;  ws += (size_t)M_ * D_ * 2;        // 64 MB
  unsigned short* G  = (unsigned short*)ws;  ws += (size_t)M_ * D_ * 2;        // 64 MB
  float* AggA = (float*)ws;                  ws += (size_t)B_ * NC_ * D_ * 4;  // 1 MB
  float* AggV = (float*)ws;                  ws += (size_t)B_ * NC_ * D_ * 4;  // 1 MB
  float* H0   = (float*)ws;                  ws += (size_t)B_ * NC_ * D_ * 4;  // 1 MB

  cast_x_kernel<<<4096, 256, 0, stream>>>(x, Xb);
  cast_wt_kernel<<<dim3(N_ / 32, K_ / 32), dim3(32, 8), 0, stream>>>(W, Wt);
  gemm_kernel<<<4096, 256, 0, stream>>>(Xb, Wt, bias, S, G);
  chunk_agg_kernel<<<dim3(D_ / 256, NC_, B_), 256, 0, stream>>>(S, G, AggA, AggV);
  chunk_scan_kernel<<<dim3(D_ / 256, B_), 256, 0, stream>>>(AggA, AggV, H0);
  scan_ln_kernel<<<dim3(NC_, B_), 1024, 0, stream>>>(S, G, x, H0, gamma, beta, out);
}